// Round 10
// baseline (138.797 us; speedup 1.0000x reference)
//
#include <hip/hip_runtime.h>

#define NODE 2048
#define KDIM 2048
#define CLUSTER 32
#define IN_DIM 64
#define OUT_DIM 64
#define BATCH 32

typedef short short8 __attribute__((ext_vector_type(8)));
typedef short short4v __attribute__((ext_vector_type(4)));
typedef float f32x4 __attribute__((ext_vector_type(4)));

__device__ __forceinline__ short f2bf(float f) {
  unsigned u = __float_as_uint(f);
  u += 0x7fffu + ((u >> 16) & 1u);   // round-to-nearest-even
  return (short)(u >> 16);
}
__device__ __forceinline__ float bf2f(short s) {
  return __uint_as_float(((unsigned)(unsigned short)s) << 16);
}

typedef __attribute__((address_space(1))) const unsigned int gu32;
typedef __attribute__((address_space(3))) unsigned int lu32;
// A-stream cache policy: NT (bit1) + SC1 (bit4) = aux 18. NT alone (R8)
// gave -25us; SC1 probes whether removing the L2 transaction entirely
// (read-around at device scope) relieves the fill path further.
__device__ __forceinline__ void gl16nt(const void* g, void* l) {
  __builtin_amdgcn_global_load_lds((gu32*)g, (lu32*)l, 16, 0, 18);
}

// ---------------------------------------------------------------------------
// k1: w = alpha @ beta, stored as bf16 in MFMA-B fragment layout (unchanged)
// ---------------------------------------------------------------------------
__global__ __launch_bounds__(256) void k1_wgen(
    const float* __restrict__ alpha, const float* __restrict__ beta,
    short8* __restrict__ w_frag) {
  const int bid = blockIdx.x;
  const int ngrp = bid >> 1;
  const int ihalf = bid & 1;
  const int t = threadIdx.x;
  const int o = t & 63;
  const int igl = t >> 6;
  const int i0 = ihalf * 32 + igl * 8;
  const int n0 = ngrp * 8;

  float acc[8][8];
#pragma unroll
  for (int r = 0; r < 8; ++r)
#pragma unroll
    for (int j = 0; j < 8; ++j) acc[r][j] = 0.f;

  for (int k = 0; k < CLUSTER; ++k) {
    float av[8];
#pragma unroll
    for (int r = 0; r < 8; ++r) av[r] = alpha[(n0 + r) * CLUSTER + k];
    const float* bp = beta + k * (IN_DIM * OUT_DIM) + i0 * OUT_DIM + o;
#pragma unroll
    for (int j = 0; j < 8; ++j) {
      float bv = bp[j * OUT_DIM];
#pragma unroll
      for (int r = 0; r < 8; ++r) acc[r][j] += av[r] * bv;
    }
  }
#pragma unroll
  for (int r = 0; r < 8; ++r) {
    short8 s;
#pragma unroll
    for (int j = 0; j < 8; ++j) s[j] = f2bf(acc[r][j]);
    w_frag[((n0 + r) * 8 + (i0 >> 3)) * 64 + o] = s;
  }
}

// ---------------------------------------------------------------------------
// k2: h2[b,n,o] = sum_i h[b,n,i]*w[n,i,o] + bias[o]  (unchanged)
// ---------------------------------------------------------------------------
__global__ __launch_bounds__(64) void k2_h2(
    const float* __restrict__ h, const short8* __restrict__ w_frag,
    const float* __restrict__ bias, short* __restrict__ h2_frag) {
  const int n = blockIdx.x;
  const int l = threadIdx.x;
  const int lr = l & 15, lk = l >> 4;

  short8 afr[2][2];
#pragma unroll
  for (int m = 0; m < 2; ++m)
#pragma unroll
    for (int kf = 0; kf < 2; ++kf) {
      const float* hp =
          h + ((size_t)(m * 16 + lr) * NODE + n) * IN_DIM + kf * 32 + lk * 8;
      f32x4 v0 = *(const f32x4*)hp;
      f32x4 v1 = *(const f32x4*)(hp + 4);
      short8 s;
#pragma unroll
      for (int j = 0; j < 4; ++j) { s[j] = f2bf(v0[j]); s[j + 4] = f2bf(v1[j]); }
      afr[m][kf] = s;
    }

  short8 bfr[4][2];
#pragma unroll
  for (int ng = 0; ng < 4; ++ng)
#pragma unroll
    for (int kf = 0; kf < 2; ++kf)
      bfr[ng][kf] = w_frag[(n * 8 + kf * 4 + lk) * 64 + ng * 16 + lr];

  f32x4 acc[2][4];
#pragma unroll
  for (int m = 0; m < 2; ++m)
#pragma unroll
    for (int ng = 0; ng < 4; ++ng) acc[m][ng] = (f32x4){0.f, 0.f, 0.f, 0.f};

#pragma unroll
  for (int kf = 0; kf < 2; ++kf)
#pragma unroll
    for (int m = 0; m < 2; ++m)
#pragma unroll
      for (int ng = 0; ng < 4; ++ng)
        acc[m][ng] = __builtin_amdgcn_mfma_f32_16x16x32_bf16(
            afr[m][kf], bfr[ng][kf], acc[m][ng], 0, 0, 0);

#pragma unroll
  for (int m = 0; m < 2; ++m)
#pragma unroll
    for (int ng = 0; ng < 4; ++ng) {
      const int o = ng * 16 + lr;
      const float bv = bias[o];
#pragma unroll
      for (int r = 0; r < 4; ++r) {
        const int b = m * 16 + lk * 4 + r;
        h2_frag[(((size_t)b * 256 + (n >> 3)) * 64 + o) * 8 + (n & 7)] =
            f2bf(acc[m][ng][r] + bv);
      }
    }
}

// ---------------------------------------------------------------------------
// k3 (hot): out[b] = a[b] @ h2[b] + h2[b]
// R8 byte-identical; ONLY change: A-load aux 2 -> 18 (NT|SC1).
// ---------------------------------------------------------------------------
__global__ __launch_bounds__(256, 4) void k3_main(
    const float* __restrict__ a, const short* __restrict__ h2f,
    float* __restrict__ out) {
  __shared__ float lds[4][2][1024];               // [wave][buf][4 KiB]
  const int bid0 = blockIdx.x;                    // 512
  const int swz = (bid0 & 7) * 64 + (bid0 >> 3);  // XCD-cluster same-batch
  const int b = swz >> 4;                         // 32 batches
  const int rt = swz & 15;                        // 16 row tiles of 128
  const int t = threadIdx.x;
  const int wid = t >> 6;
  const int l = t & 63;
  const int lr = l & 15, lk = l >> 4;
  const int sw = l & 7;
  const int rowbase = rt * 128 + wid * 32;
  const int s0 = ((swz * 4 + wid) * 37) & 63;     // per-wave K-phase stagger

  const char* gA = (const char*)(a + (size_t)b * NODE * KDIM
                                   + (size_t)(rowbase + (l >> 3)) * KDIM)
                   + (size_t)(((l & 7) ^ (l >> 3)) * 16);
  const short8* bbase = (const short8*)h2f + ((size_t)b * 256 + lk) * 64 + lr;

  char* ldsb0 = (char*)&lds[wid][0][0];
  char* ldsb1 = (char*)&lds[wid][1][0];
  const int O00 = lr * 128 + ((2 * lk + 0) ^ sw) * 16;
  const int O01 = lr * 128 + ((2 * lk + 1) ^ sw) * 16;
  const int O10 = (16 + lr) * 128 + ((2 * lk + 0) ^ sw) * 16;
  const int O11 = (16 + lr) * 128 + ((2 * lk + 1) ^ sw) * 16;

  f32x4 acc[2][4];
#pragma unroll
  for (int m = 0; m < 2; ++m)
#pragma unroll
    for (int ng = 0; ng < 4; ++ng) acc[m][ng] = (f32x4){0.f, 0.f, 0.f, 0.f};

  short8 BE[4], BO[4];

#define ISSUE_A(s, LP)                                   \
  do {                                                   \
    const int ss_ = ((s) + s0) & 63;                     \
    const char* g_ = gA + (size_t)ss_ * 128;             \
    gl16nt(g_ + 0 * 65536, (LP) + 0 * 1024);             \
    gl16nt(g_ + 1 * 65536, (LP) + 1 * 1024);             \
    gl16nt(g_ + 2 * 65536, (LP) + 2 * 1024);             \
    gl16nt(g_ + 3 * 65536, (LP) + 3 * 1024);             \
  } while (0)

#define ISSUE_B(s, BR)                                   \
  do {                                                   \
    const int ss_ = ((s) + s0) & 63;                     \
    const short8* q_ = bbase + ss_ * 256;                \
    BR[0] = q_[0];                                       \
    BR[1] = q_[16];                                      \
    BR[2] = q_[32];                                      \
    BR[3] = q_[48];                                      \
  } while (0)

#define COMPUTE(LP, BR)                                                     \
  do {                                                                      \
    f32x4 m0h0 = *(const f32x4*)((LP) + O00);                               \
    f32x4 m0h1 = *(const f32x4*)((LP) + O01);                               \
    f32x4 m1h0 = *(const f32x4*)((LP) + O10);                               \
    f32x4 m1h1 = *(const f32x4*)((LP) + O11);                               \
    short8 af0, af1;                                                        \
    _Pragma("unroll") for (int j_ = 0; j_ < 4; ++j_) {                      \
      af0[j_] = f2bf(m0h0[j_]);                                             \
      af0[j_ + 4] = f2bf(m0h1[j_]);                                         \
      af1[j_] = f2bf(m1h0[j_]);                                             \
      af1[j_ + 4] = f2bf(m1h1[j_]);                                         \
    }                                                                       \
    _Pragma("unroll") for (int ng_ = 0; ng_ < 4; ++ng_) {                   \
      acc[0][ng_] = __builtin_amdgcn_mfma_f32_16x16x32_bf16(                \
          af0, BR[ng_], acc[0][ng_], 0, 0, 0);                              \
      acc[1][ng_] = __builtin_amdgcn_mfma_f32_16x16x32_bf16(                \
          af1, BR[ng_], acc[1][ng_], 0, 0, 0);                              \
    }                                                                       \
  } while (0)

  // prologue: stage s0 -> buf0/BE
  ISSUE_A(0, ldsb0);
  ISSUE_B(0, BE);

#pragma unroll 1
  for (int u = 0; u < 32; ++u) {
    ISSUE_A(2 * u + 1, ldsb1);
    ISSUE_B(2 * u + 1, BO);
    asm volatile("s_waitcnt vmcnt(8)" ::: "memory");
    __builtin_amdgcn_sched_barrier(0);
    COMPUTE(ldsb0, BE);
    if (u < 31) {
      ISSUE_A(2 * u + 2, ldsb0);
      ISSUE_B(2 * u + 2, BE);
      asm volatile("s_waitcnt vmcnt(8)" ::: "memory");
    } else {
      asm volatile("s_waitcnt vmcnt(0)" ::: "memory");
    }
    __builtin_amdgcn_sched_barrier(0);
    COMPUTE(ldsb1, BO);
  }
#undef ISSUE_A
#undef ISSUE_B
#undef COMPUTE

  // epilogue: residual (+h2) fused; 8-B vector residual reads
#pragma unroll
  for (int m = 0; m < 2; ++m) {
    const int row0 = rowbase + m * 16 + lk * 4;
#pragma unroll
    for (int ng = 0; ng < 4; ++ng) {
      const int col = ng * 16 + lr;
      const short4v rv = *(const short4v*)&h2f[
          (((size_t)b * 256 + (row0 >> 3)) * 64 + col) * 8 + (row0 & 7)];
#pragma unroll
      for (int r = 0; r < 4; ++r) {
        out[((size_t)b * NODE + row0 + r) * 64 + col] =
            acc[m][ng][r] + bf2f(rv[r]);
      }
    }
  }
}

extern "C" void kernel_launch(void* const* d_in, const int* in_sizes, int n_in,
                              void* d_out, int out_size, void* d_ws, size_t ws_size,
                              hipStream_t stream) {
  const float* a     = (const float*)d_in[0];
  const float* h     = (const float*)d_in[1];
  const float* alpha = (const float*)d_in[2];
  const float* beta  = (const float*)d_in[3];
  const float* bias  = (const float*)d_in[4];
  float* out = (float*)d_out;

  short8* w_frag = (short8*)d_ws;
  short*  h2_frag = (short*)((char*)d_ws + (size_t)(16u << 20));

  k1_wgen<<<dim3(512), dim3(256), 0, stream>>>(alpha, beta, w_frag);
  k2_h2 <<<dim3(NODE), dim3(64),  0, stream>>>(h, w_frag, bias, h2_frag);
  k3_main<<<dim3(512), dim3(256), 0, stream>>>(a, h2_frag, out);
}

// Round 11
// 133.299 us; speedup vs baseline: 1.0412x; 1.0412x over previous
//
#include <hip/hip_runtime.h>

#define NODE 2048
#define KDIM 2048
#define CLUSTER 32
#define IN_DIM 64
#define OUT_DIM 64
#define BATCH 32

typedef short short8 __attribute__((ext_vector_type(8)));
typedef short short4v __attribute__((ext_vector_type(4)));
typedef float f32x4 __attribute__((ext_vector_type(4)));

__device__ __forceinline__ short f2bf(float f) {
  unsigned u = __float_as_uint(f);
  u += 0x7fffu + ((u >> 16) & 1u);   // round-to-nearest-even
  return (short)(u >> 16);
}
__device__ __forceinline__ float bf2f(short s) {
  return __uint_as_float(((unsigned)(unsigned short)s) << 16);
}

typedef __attribute__((address_space(1))) const unsigned int gu32;
typedef __attribute__((address_space(3))) unsigned int lu32;
// NT (evict-first) on the zero-reuse A stream: R8's -25us win. SC1 was null.
__device__ __forceinline__ void gl16nt(const void* g, void* l) {
  __builtin_amdgcn_global_load_lds((gu32*)g, (lu32*)l, 16, 0, 2);
}

// ---------------------------------------------------------------------------
// k12: FUSED w-gen + h2.  Block = 8 nodes.
//  Phase A: w[n] = alpha[n,:] @ beta into LDS (w_frag fragment layout,
//           bit-identical FMA order to the old k1; beta is L2-resident).
//  Phase B: 4 waves x 2 nodes each run the old k2 body with B-frags from LDS.
// Deletes the 16 MiB w_frag HBM write + 16 MiB read + one kernel launch.
// ---------------------------------------------------------------------------
__global__ __launch_bounds__(256) void k12_wh2(
    const float* __restrict__ alpha, const float* __restrict__ beta,
    const float* __restrict__ h, const float* __restrict__ bias,
    short* __restrict__ h2_frag) {
  __shared__ short8 w_lds[4096];   // [(r*8 + f)*64 + o], exactly 64 KiB
  const int bid = blockIdx.x;      // 256
  const int n0 = bid * 8;
  const int t = threadIdx.x;
  const int o = t & 63;
  const int wid = t >> 6;          // wave id = igl

  // ---- phase A: w for 8 nodes (thread = (o, igl); loop ihalf) ----
#pragma unroll 1
  for (int ihalf = 0; ihalf < 2; ++ihalf) {
    const int i0 = ihalf * 32 + wid * 8;
    float acc[8][8];
#pragma unroll
    for (int r = 0; r < 8; ++r)
#pragma unroll
      for (int j = 0; j < 8; ++j) acc[r][j] = 0.f;

    for (int k = 0; k < CLUSTER; ++k) {
      float av[8];
#pragma unroll
      for (int r = 0; r < 8; ++r) av[r] = alpha[(n0 + r) * CLUSTER + k];
      const float* bp = beta + k * (IN_DIM * OUT_DIM) + i0 * OUT_DIM + o;
#pragma unroll
      for (int j = 0; j < 8; ++j) {
        float bv = bp[j * OUT_DIM];
#pragma unroll
        for (int r = 0; r < 8; ++r) acc[r][j] += av[r] * bv;
      }
    }
#pragma unroll
    for (int r = 0; r < 8; ++r) {
      short8 s;
#pragma unroll
      for (int j = 0; j < 8; ++j) s[j] = f2bf(acc[r][j]);
      w_lds[(r * 8 + (i0 >> 3)) * 64 + o] = s;
    }
  }
  __syncthreads();

  // ---- phase B: h2 for nodes n0+2*wid, n0+2*wid+1 (old k2 body) ----
  const int l = t & 63;
  const int lr = l & 15, lk = l >> 4;
#pragma unroll 1
  for (int rl = 0; rl < 2; ++rl) {
    const int rloc = wid * 2 + rl;
    const int n = n0 + rloc;

    short8 afr[2][2];
#pragma unroll
    for (int m = 0; m < 2; ++m)
#pragma unroll
      for (int kf = 0; kf < 2; ++kf) {
        const float* hp =
            h + ((size_t)(m * 16 + lr) * NODE + n) * IN_DIM + kf * 32 + lk * 8;
        f32x4 v0 = *(const f32x4*)hp;
        f32x4 v1 = *(const f32x4*)(hp + 4);
        short8 s;
#pragma unroll
        for (int j = 0; j < 4; ++j) { s[j] = f2bf(v0[j]); s[j + 4] = f2bf(v1[j]); }
        afr[m][kf] = s;
      }

    short8 bfr[4][2];
#pragma unroll
    for (int ng = 0; ng < 4; ++ng)
#pragma unroll
      for (int kf = 0; kf < 2; ++kf)
        bfr[ng][kf] = w_lds[(rloc * 8 + kf * 4 + lk) * 64 + ng * 16 + lr];

    f32x4 acc[2][4];
#pragma unroll
    for (int m = 0; m < 2; ++m)
#pragma unroll
      for (int ng = 0; ng < 4; ++ng) acc[m][ng] = (f32x4){0.f, 0.f, 0.f, 0.f};

#pragma unroll
    for (int kf = 0; kf < 2; ++kf)
#pragma unroll
      for (int m = 0; m < 2; ++m)
#pragma unroll
        for (int ng = 0; ng < 4; ++ng)
          acc[m][ng] = __builtin_amdgcn_mfma_f32_16x16x32_bf16(
              afr[m][kf], bfr[ng][kf], acc[m][ng], 0, 0, 0);

#pragma unroll
    for (int m = 0; m < 2; ++m)
#pragma unroll
      for (int ng = 0; ng < 4; ++ng) {
        const int oo = ng * 16 + lr;
        const float bv = bias[oo];
#pragma unroll
        for (int r = 0; r < 4; ++r) {
          const int b = m * 16 + lk * 4 + r;
          h2_frag[(((size_t)b * 256 + (n >> 3)) * 64 + oo) * 8 + (n & 7)] =
              f2bf(acc[m][ng][r] + bv);
        }
      }
  }
}

// ---------------------------------------------------------------------------
// k3 (hot): out[b] = a[b] @ h2[b] + h2[b]  — byte-identical to R8 (best).
// ---------------------------------------------------------------------------
__global__ __launch_bounds__(256, 4) void k3_main(
    const float* __restrict__ a, const short* __restrict__ h2f,
    float* __restrict__ out) {
  __shared__ float lds[4][2][1024];               // [wave][buf][4 KiB]
  const int bid0 = blockIdx.x;                    // 512
  const int swz = (bid0 & 7) * 64 + (bid0 >> 3);  // XCD-cluster same-batch
  const int b = swz >> 4;                         // 32 batches
  const int rt = swz & 15;                        // 16 row tiles of 128
  const int t = threadIdx.x;
  const int wid = t >> 6;
  const int l = t & 63;
  const int lr = l & 15, lk = l >> 4;
  const int sw = l & 7;
  const int rowbase = rt * 128 + wid * 32;
  const int s0 = ((swz * 4 + wid) * 37) & 63;     // per-wave K-phase stagger

  const char* gA = (const char*)(a + (size_t)b * NODE * KDIM
                                   + (size_t)(rowbase + (l >> 3)) * KDIM)
                   + (size_t)(((l & 7) ^ (l >> 3)) * 16);
  const short8* bbase = (const short8*)h2f + ((size_t)b * 256 + lk) * 64 + lr;

  char* ldsb0 = (char*)&lds[wid][0][0];
  char* ldsb1 = (char*)&lds[wid][1][0];
  const int O00 = lr * 128 + ((2 * lk + 0) ^ sw) * 16;
  const int O01 = lr * 128 + ((2 * lk + 1) ^ sw) * 16;
  const int O10 = (16 + lr) * 128 + ((2 * lk + 0) ^ sw) * 16;
  const int O11 = (16 + lr) * 128 + ((2 * lk + 1) ^ sw) * 16;

  f32x4 acc[2][4];
#pragma unroll
  for (int m = 0; m < 2; ++m)
#pragma unroll
    for (int ng = 0; ng < 4; ++ng) acc[m][ng] = (f32x4){0.f, 0.f, 0.f, 0.f};

  short8 BE[4], BO[4];

#define ISSUE_A(s, LP)                                   \
  do {                                                   \
    const int ss_ = ((s) + s0) & 63;                     \
    const char* g_ = gA + (size_t)ss_ * 128;             \
    gl16nt(g_ + 0 * 65536, (LP) + 0 * 1024);             \
    gl16nt(g_ + 1 * 65536, (LP) + 1 * 1024);             \
    gl16nt(g_ + 2 * 65536, (LP) + 2 * 1024);             \
    gl16nt(g_ + 3 * 65536, (LP) + 3 * 1024);             \
  } while (0)

#define ISSUE_B(s, BR)                                   \
  do {                                                   \
    const int ss_ = ((s) + s0) & 63;                     \
    const short8* q_ = bbase + ss_ * 256;                \
    BR[0] = q_[0];                                       \
    BR[1] = q_[16];                                      \
    BR[2] = q_[32];                                      \
    BR[3] = q_[48];                                      \
  } while (0)

#define COMPUTE(LP, BR)                                                     \
  do {                                                                      \
    f32x4 m0h0 = *(const f32x4*)((LP) + O00);                               \
    f32x4 m0h1 = *(const f32x4*)((LP) + O01);                               \
    f32x4 m1h0 = *(const f32x4*)((LP) + O10);                               \
    f32x4 m1h1 = *(const f32x4*)((LP) + O11);                               \
    short8 af0, af1;                                                        \
    _Pragma("unroll") for (int j_ = 0; j_ < 4; ++j_) {                      \
      af0[j_] = f2bf(m0h0[j_]);                                             \
      af0[j_ + 4] = f2bf(m0h1[j_]);                                         \
      af1[j_] = f2bf(m1h0[j_]);                                             \
      af1[j_ + 4] = f2bf(m1h1[j_]);                                         \
    }                                                                       \
    _Pragma("unroll") for (int ng_ = 0; ng_ < 4; ++ng_) {                   \
      acc[0][ng_] = __builtin_amdgcn_mfma_f32_16x16x32_bf16(                \
          af0, BR[ng_], acc[0][ng_], 0, 0, 0);                              \
      acc[1][ng_] = __builtin_amdgcn_mfma_f32_16x16x32_bf16(                \
          af1, BR[ng_], acc[1][ng_], 0, 0, 0);                              \
    }                                                                       \
  } while (0)

  // prologue: stage s0 -> buf0/BE
  ISSUE_A(0, ldsb0);
  ISSUE_B(0, BE);

#pragma unroll 1
  for (int u = 0; u < 32; ++u) {
    ISSUE_A(2 * u + 1, ldsb1);
    ISSUE_B(2 * u + 1, BO);
    asm volatile("s_waitcnt vmcnt(8)" ::: "memory");
    __builtin_amdgcn_sched_barrier(0);
    COMPUTE(ldsb0, BE);
    if (u < 31) {
      ISSUE_A(2 * u + 2, ldsb0);
      ISSUE_B(2 * u + 2, BE);
      asm volatile("s_waitcnt vmcnt(8)" ::: "memory");
    } else {
      asm volatile("s_waitcnt vmcnt(0)" ::: "memory");
    }
    __builtin_amdgcn_sched_barrier(0);
    COMPUTE(ldsb1, BO);
  }
#undef ISSUE_A
#undef ISSUE_B
#undef COMPUTE

  // epilogue: residual (+h2) fused; 8-B vector residual reads
#pragma unroll
  for (int m = 0; m < 2; ++m) {
    const int row0 = rowbase + m * 16 + lk * 4;
#pragma unroll
    for (int ng = 0; ng < 4; ++ng) {
      const int col = ng * 16 + lr;
      const short4v rv = *(const short4v*)&h2f[
          (((size_t)b * 256 + (row0 >> 3)) * 64 + col) * 8 + (row0 & 7)];
#pragma unroll
      for (int r = 0; r < 4; ++r) {
        out[((size_t)b * NODE + row0 + r) * 64 + col] =
            acc[m][ng][r] + bf2f(rv[r]);
      }
    }
  }
}

extern "C" void kernel_launch(void* const* d_in, const int* in_sizes, int n_in,
                              void* d_out, int out_size, void* d_ws, size_t ws_size,
                              hipStream_t stream) {
  const float* a     = (const float*)d_in[0];
  const float* h     = (const float*)d_in[1];
  const float* alpha = (const float*)d_in[2];
  const float* beta  = (const float*)d_in[3];
  const float* bias  = (const float*)d_in[4];
  float* out = (float*)d_out;

  short* h2_frag = (short*)((char*)d_ws + (size_t)(16u << 20));

  k12_wh2<<<dim3(256), dim3(256), 0, stream>>>(alpha, beta, h, bias, h2_frag);
  k3_main<<<dim3(512), dim3(256), 0, stream>>>(a, h2_frag, out);
}